// Round 6
// baseline (856.141 us; speedup 1.0000x reference)
//
#include <hip/hip_runtime.h>
#include <hip/hip_bf16.h>
#include <hip/hip_fp16.h>

#define Hh 128
#define Ww 160
#define Cc 32
#define Dd 48
#define Bb 2
#define Vv 3
#define HW (Hh*Ww)
#define VS 32      // vsh channel stride in f16 units: XOR swizzle keeps banks spread
#define GRID 1024  // 4 blocks/CU x 256 CU; __launch_bounds__(256,4) + 31.2KB LDS guarantee co-residency

typedef _Float16 f16x8 __attribute__((ext_vector_type(8)));
typedef float f32x4 __attribute__((ext_vector_type(4)));

// Software grid barrier (graph-capturable replacement for cooperative sync).
// Producer: __threadfence (agent-scope, flushes XCD-L2) + device-scope atomic
// arrive. Last block sets release flag; all spin on it. Consumer-side fence
// after release, executed by every thread, precedes dependent loads.
__device__ __forceinline__ void grid_barrier(unsigned int* bar) {
    __syncthreads();
    if (threadIdx.x == 0) {
        __threadfence();
        unsigned prev = __hip_atomic_fetch_add(bar, 1u, __ATOMIC_ACQ_REL,
                                               __HIP_MEMORY_SCOPE_AGENT);
        if (prev == GRID - 1) {
            __hip_atomic_store(bar + 16, 1u, __ATOMIC_RELEASE,
                               __HIP_MEMORY_SCOPE_AGENT);
        } else {
            while (!__hip_atomic_load(bar + 16, __ATOMIC_ACQUIRE,
                                      __HIP_MEMORY_SCOPE_AGENT)) {
                __builtin_amdgcn_s_sleep(2);
            }
        }
    }
    __syncthreads();
    __threadfence();
}

// ---------------- fused pipeline: transpose -> bar -> main -> bar -> post ---
// R18: same fusion as R17 (the constant ~70us non-k_main residue across
// R12-R16 is the target) but with a plain launch + software grid barrier,
// since hipLaunchCooperativeKernel is not graph-capturable in this harness
// (R17: silent no-op launch, absmax 788 = untouched zero output buffer).
__global__ __launch_bounds__(256, 4)
void k_fused(const float* __restrict__ f, const float* __restrict__ pm,
             const float* __restrict__ wt, const float* __restrict__ dvals,
             ushort* __restrict__ featT, float* __restrict__ P,
             ushort* __restrict__ Bfr, ushort* __restrict__ S,
             unsigned int* __restrict__ bars, float* __restrict__ out) {
    __shared__ __align__(16) char smem[31232];
    const int tid = threadIdx.x;
    const int bid = blockIdx.x;

    // ================= phase 0: transpose (v,b,c,h,w) f32 -> (v,b,h,w,c) f16
    if (bid == 0 && tid < 64) {
        if (tid < Bb * (Vv - 1)) {
            int b = tid >> 1;
            int v = (tid & 1) + 1;
            const float* ref = pm + (b * Vv + 0) * 16;
            const float* src = pm + (b * Vv + v) * 16;
            float A[4][8];
            for (int i = 0; i < 4; ++i)
                for (int j = 0; j < 4; ++j) {
                    A[i][j] = ref[i * 4 + j];
                    A[i][4 + j] = (i == j) ? 1.0f : 0.0f;
                }
            for (int col = 0; col < 4; ++col) {
                int piv = col;
                for (int r = col + 1; r < 4; ++r)
                    if (fabsf(A[r][col]) > fabsf(A[piv][col])) piv = r;
                if (piv != col)
                    for (int j = 0; j < 8; ++j) { float tmp = A[col][j]; A[col][j] = A[piv][j]; A[piv][j] = tmp; }
                float inv = 1.0f / A[col][col];
                for (int j = 0; j < 8; ++j) A[col][j] *= inv;
                for (int r = 0; r < 4; ++r) {
                    if (r == col) continue;
                    float fct = A[r][col];
                    for (int j = 0; j < 8; ++j) A[r][j] -= fct * A[col][j];
                }
            }
            float Pm[3][4];
            for (int i = 0; i < 3; ++i)
                for (int j = 0; j < 4; ++j) {
                    float s = 0.f;
                    for (int k = 0; k < 4; ++k) s += src[i * 4 + k] * A[k][4 + j];
                    Pm[i][j] = s;
                }
            float* o = P + tid * 12;
            o[0] = Pm[0][0]; o[1] = Pm[0][1]; o[2] = Pm[0][2];
            o[3] = Pm[1][0]; o[4] = Pm[1][1]; o[5] = Pm[1][2];
            o[6] = Pm[2][0]; o[7] = Pm[2][1]; o[8] = Pm[2][2];
            o[9] = Pm[0][3]; o[10] = Pm[1][3]; o[11] = Pm[2][3];
        }
        int kd = tid & 15, q = tid >> 4;
        for (int tap = 0; tap < 9; ++tap) {
            ushort* dst = Bfr + (tap * 64 + tid) * 8;
            for (int j = 0; j < 8; ++j) {
                float w = (kd < 3) ? wt[(q * 8 + j) * 27 + kd * 9 + tap] : 0.f;
                __half h = __float2half(w);
                dst[j] = *(ushort*)&h;
            }
        }
    }
    if (bid < Vv * Bb * Hh) {
        float (*t)[Ww + 1] = (float(*)[Ww + 1])smem;
        int vb = bid / Hh, y = bid % Hh;
        const float* src = f + (size_t)vb * Cc * HW + (size_t)y * Ww;
        ushort* dst = featT + ((size_t)vb * Hh + y) * Ww * Cc;
        for (int i = tid; i < Cc * (Ww / 4); i += 256) {
            int c = i / (Ww / 4), x4 = (i - c * (Ww / 4)) * 4;
            float4 v = *(const float4*)(src + (size_t)c * HW + x4);
            t[c][x4] = v.x; t[c][x4 + 1] = v.y; t[c][x4 + 2] = v.z; t[c][x4 + 3] = v.w;
        }
        __syncthreads();
        for (int i = tid; i < Ww * 4; i += 256) {
            int x = i >> 2, c8 = i & 3;
            union { uint4 u; ushort s[8]; } pk;
#pragma unroll
            for (int j = 0; j < 8; ++j) {
                __half h = __float2half(t[c8 * 8 + j][x]);
                pk.s[j] = *(ushort*)&h;
            }
            *(uint4*)&dst[x * Cc + c8 * 8] = pk.u;
        }
    }
    grid_barrier(bars);

    // ================= phase 1: variance + MFMA conv (R12 body, grid-strided)
    {
        ushort* vsh = (ushort*)smem;                        // 324*32 f16 = 20736B
        unsigned int* offs = (unsigned int*)(smem + 20736); // 324*4 u32 = 5184B
        unsigned int* wgts = (unsigned int*)(smem + 25920); // 324*4 u32 = 5184B
        float* rt = (float*)(smem + 31104);                 // 24 floats
        const int lane = tid & 63;
        const int wave = tid >> 6;
        const int q = lane >> 4;
        const int n = lane & 15;
        uint4 bf[9];
#pragma unroll
        for (int tap = 0; tap < 9; ++tap)
            bf[tap] = *(const uint4*)(Bfr + ((tap * 64 + lane) << 3));

#pragma unroll 1
        for (int vb = bid; vb < 80 * Dd * Bb; vb += GRID) {
            const int tile = vb % 80;
            const int rem = vb / 80;
            const int d = rem % Dd;
            const int b = rem / Dd;
            const int tileY = tile / 10, tileX = tile - (tile / 10) * 10;

            if (tid < 24) rt[tid] = P[b * 24 + tid];
            const float depth = dvals[b * Dd + d];
            __syncthreads();

            // ---- stage A: bilinear coords for all 324 slots ----
#pragma unroll 1
            for (int p = tid; p < 324; p += 256) {
                int pyt = p / 18, pxt = p - pyt * 18;
                int gy = tileY * 16 + pyt - 1, gx = tileX * 16 + pxt - 1;
                if ((unsigned)gy >= (unsigned)Hh || (unsigned)gx >= (unsigned)Ww) continue;
#pragma unroll
                for (int vi = 0; vi < 2; ++vi) {
                    const float* M = &rt[vi * 12];
                    float fgx = (float)gx, fgy = (float)gy;
                    float rx = M[0] * fgx + M[1] * fgy + M[2];
                    float ry = M[3] * fgx + M[4] * fgy + M[5];
                    float rz = M[6] * fgx + M[7] * fgy + M[8];
                    float X = rx * depth + M[9];
                    float Y = ry * depth + M[10];
                    float Z = rz * depth + M[11];
                    float z = (fabsf(Z) < 1e-6f) ? 1e-6f : Z;
                    float u = X / z, vv = Y / z;
                    float x0f = floorf(u), y0f = floorf(vv);
                    float fx = u - x0f, fy = vv - y0f;
                    int x0 = (int)x0f, y0 = (int)y0f;
                    int x1 = x0 + 1, y1 = y0 + 1;
                    bool vx0 = (x0 >= 0) && (x0 <= Ww - 1);
                    bool vx1 = (x1 >= 0) && (x1 <= Ww - 1);
                    bool vy0 = (y0 >= 0) && (y0 <= Hh - 1);
                    bool vy1 = (y1 >= 0) && (y1 <= Hh - 1);
                    int xc0 = min(max(x0, 0), Ww - 1), xc1 = min(max(x1, 0), Ww - 1);
                    int yc0 = min(max(y0, 0), Hh - 1), yc1 = min(max(y1, 0), Hh - 1);
                    unsigned int p00 = (unsigned)(yc0 * Ww + xc0);
                    unsigned int p01 = (unsigned)(yc0 * Ww + xc1);
                    unsigned int p10 = (unsigned)(yc1 * Ww + xc0);
                    unsigned int p11 = (unsigned)(yc1 * Ww + xc1);
                    float w0 = (vx0 && vy0) ? (1.f - fx) * (1.f - fy) : 0.f;
                    float w1 = (vx1 && vy0) ? fx * (1.f - fy) : 0.f;
                    float w2 = (vx0 && vy1) ? (1.f - fx) * fy : 0.f;
                    float w3 = (vx1 && vy1) ? fx * fy : 0.f;
                    offs[p * 4 + vi * 2 + 0] = p00 | (p01 << 16);
                    offs[p * 4 + vi * 2 + 1] = p10 | (p11 << 16);
                    __half2 ha = __floats2half2_rn(w0, w1);
                    __half2 hb = __floats2half2_rn(w2, w3);
                    wgts[p * 4 + vi * 2 + 0] = *(unsigned int*)&ha;
                    wgts[p * 4 + vi * 2 + 1] = *(unsigned int*)&hb;
                }
            }
            __syncthreads();

            const ushort* b1 = featT + (size_t)(1 * Bb + b) * HW * Cc;
            const ushort* b2 = featT + (size_t)(2 * Bb + b) * HW * Cc;
            const ushort* br = featT + (size_t)b * HW * Cc;

            // ---- stage B: gather items (slot, c16 0..1): 648 items ----
#pragma unroll 1
            for (int i = tid; i < 648; i += 256) {
                int p = i >> 1, half16 = i & 1;
                int c16 = half16 << 4;
                int pyt = p / 18, pxt = p - pyt * 18;
                int gy = tileY * 16 + pyt - 1, gx = tileX * 16 + pxt - 1;
                int sw0 = ((half16 * 2 + 0) ^ (p & 3)) * 8;
                int sw1 = ((half16 * 2 + 1) ^ (p & 3)) * 8;
                ushort* dst0 = &vsh[p * VS + sw0];
                ushort* dst1 = &vsh[p * VS + sw1];
                if ((unsigned)gy >= (unsigned)Hh || (unsigned)gx >= (unsigned)Ww) {
                    *(uint4*)dst0 = make_uint4(0u, 0u, 0u, 0u);
                    *(uint4*)dst1 = make_uint4(0u, 0u, 0u, 0u);
                    continue;
                }
                uint4 oo = *(const uint4*)&offs[p * 4];
                uint4 wwp = *(const uint4*)&wgts[p * 4];
                int o00 = (int)(oo.x & 0xffffu) * Cc + c16;
                int o01 = (int)(oo.x >> 16)     * Cc + c16;
                int o10 = (int)(oo.y & 0xffffu) * Cc + c16;
                int o11 = (int)(oo.y >> 16)     * Cc + c16;
                int o20 = (int)(oo.z & 0xffffu) * Cc + c16;
                int o21 = (int)(oo.z >> 16)     * Cc + c16;
                int o30 = (int)(oo.w & 0xffffu) * Cc + c16;
                int o31 = (int)(oo.w >> 16)     * Cc + c16;
                int orf = (gy * Ww + gx) * Cc + c16;
                __half2 hv0 = *(__half2*)&wwp.x;
                __half2 hv1 = *(__half2*)&wwp.y;
                __half2 hv2 = *(__half2*)&wwp.z;
                __half2 hv3 = *(__half2*)&wwp.w;
                __half2 w00 = __half2half2(__low2half(hv0)), w01 = __half2half2(__high2half(hv0));
                __half2 w02 = __half2half2(__low2half(hv1)), w03 = __half2half2(__high2half(hv1));
                __half2 w10 = __half2half2(__low2half(hv2)), w11 = __half2half2(__high2half(hv2));
                __half2 w12 = __half2half2(__low2half(hv3)), w13 = __half2half2(__high2half(hv3));
                const __half2 third2 = __float2half2_rn(1.0f / 3.0f);
                union U { uint4 u; __half2 h[4]; };
#pragma unroll
                for (int h = 0; h < 2; ++h) {
                    int e = h * 8;
                    U R, C0, C1, C2, C3, E0, E1, E2, E3, V;
                    R.u  = *(const uint4*)(br + orf + e);
                    C0.u = *(const uint4*)(b1 + o00 + e);
                    C1.u = *(const uint4*)(b1 + o01 + e);
                    C2.u = *(const uint4*)(b1 + o10 + e);
                    C3.u = *(const uint4*)(b1 + o11 + e);
                    E0.u = *(const uint4*)(b2 + o20 + e);
                    E1.u = *(const uint4*)(b2 + o21 + e);
                    E2.u = *(const uint4*)(b2 + o30 + e);
                    E3.u = *(const uint4*)(b2 + o31 + e);
#pragma unroll
                    for (int k = 0; k < 4; ++k) {
                        __half2 s1 = __hmul2(w00, C0.h[k]);
                        s1 = __hfma2(w01, C1.h[k], s1);
                        s1 = __hfma2(w02, C2.h[k], s1);
                        s1 = __hfma2(w03, C3.h[k], s1);
                        __half2 s2 = __hmul2(w10, E0.h[k]);
                        s2 = __hfma2(w11, E1.h[k], s2);
                        s2 = __hfma2(w12, E2.h[k], s2);
                        s2 = __hfma2(w13, E3.h[k], s2);
                        __half2 r = R.h[k];
                        __half2 sum = __hadd2(__hadd2(r, s1), s2);
                        __half2 sq = __hmul2(r, r);
                        sq = __hfma2(s1, s1, sq);
                        sq = __hfma2(s2, s2, sq);
                        __half2 m = __hmul2(sum, third2);
                        __half2 var = __hfma2(__hneg2(m), m, __hmul2(sq, third2));
                        V.h[k] = var;
                    }
                    *(uint4*)(h ? dst1 : dst0) = V.u;
                }
            }
            __syncthreads();

            // ---- MFMA conv: wave covers 4 row-groups of 16 pixels ----
#pragma unroll 1
            for (int rr = 0; rr < 4; ++rr) {
                int row = wave * 4 + rr;
                f32x4 acc = {0.f, 0.f, 0.f, 0.f};
#pragma unroll
                for (int tap = 0; tap < 9; ++tap) {
                    int kh = tap / 3, kw = tap - 3 * (tap / 3);
                    int slot = (row + kh) * 18 + n + kw;
                    union { uint4 u; f16x8 v; } A, Bf;
                    A.u  = *(const uint4*)&vsh[slot * VS + (q ^ (slot & 3)) * 8];
                    Bf.u = bf[tap];
                    acc = __builtin_amdgcn_mfma_f32_16x16x32_f16(A.v, Bf.v, acc, 0, 0, 0);
                }
                if (n < 3) {
                    int gy = tileY * 16 + row;
                    int gxb = tileX * 16 + q * 4;
                    union { uint2 u; ushort s[4]; } pk;
#pragma unroll
                    for (int j = 0; j < 4; ++j) {
                        __half h = __float2half(acc[j]);
                        pk.s[j] = *(ushort*)&h;
                    }
                    *(uint2*)&S[((size_t)(b * 3 + n) * Dd + d) * HW + (size_t)gy * Ww + gxb] = pk.u;
                }
            }
            __syncthreads();
        }
    }
    grid_barrier(bars + 64);

    // ================= phase 2: cost, softmax, depth + conf =================
    if (bid < (Bb * HW) / 128) {
        const int lane = tid & 63, wave = tid >> 6;
        const int q = lane >> 4;
        const int pl = lane & 15;
        int gid = ((bid * 4 + wave) * 16 + pl) * 2;
        int b = gid / HW;
        int pix = gid - b * HW;
        const ushort* S0 = S + ((size_t)(b * 3 + 0) * Dd) * HW + pix;
        const ushort* S1 = S + ((size_t)(b * 3 + 1) * Dd) * HW + pix;
        const ushort* S2 = S + ((size_t)(b * 3 + 2) * Dd) * HW + pix;
        const int d0 = q * 12;
        float2 cost[12];
#pragma unroll
        for (int j = 0; j < 12; ++j) {
            int dd = d0 + j;
            float2 c = __half22float2(*(const __half2*)&S1[(size_t)dd * HW]);
            if (dd > 0) {
                float2 a = __half22float2(*(const __half2*)&S0[(size_t)(dd - 1) * HW]);
                c.x += a.x; c.y += a.y;
            }
            if (dd < Dd - 1) {
                float2 a = __half22float2(*(const __half2*)&S2[(size_t)(dd + 1) * HW]);
                c.x += a.x; c.y += a.y;
            }
            cost[j] = c;
        }
        float mx = cost[0].x, my = cost[0].y;
#pragma unroll
        for (int j = 1; j < 12; ++j) { mx = fmaxf(mx, cost[j].x); my = fmaxf(my, cost[j].y); }
        mx = fmaxf(mx, __shfl_xor(mx, 16)); mx = fmaxf(mx, __shfl_xor(mx, 32));
        my = fmaxf(my, __shfl_xor(my, 16)); my = fmaxf(my, __shfl_xor(my, 32));
        float sx = 0.f, sy = 0.f, depx = 0.f, depy = 0.f, dix = 0.f, diy = 0.f;
#pragma unroll
        for (int j = 0; j < 12; ++j) {
            float dv = dvals[b * Dd + d0 + j];
            float fd = (float)(d0 + j);
            float ex = __expf(cost[j].x - mx);
            float ey = __expf(cost[j].y - my);
            cost[j].x = ex; cost[j].y = ey;
            sx += ex; sy += ey;
            depx += ex * dv; depy += ey * dv;
            dix += ex * fd;  diy += ey * fd;
        }
        sx += __shfl_xor(sx, 16); sx += __shfl_xor(sx, 32);
        sy += __shfl_xor(sy, 16); sy += __shfl_xor(sy, 32);
        depx += __shfl_xor(depx, 16); depx += __shfl_xor(depx, 32);
        depy += __shfl_xor(depy, 16); depy += __shfl_xor(depy, 32);
        dix += __shfl_xor(dix, 16); dix += __shfl_xor(dix, 32);
        diy += __shfl_xor(diy, 16); diy += __shfl_xor(diy, 32);
        float invx = 1.0f / sx, invy = 1.0f / sy;
        int didx = min(max((int)(dix * invx), 0), Dd - 1);
        int didy = min(max((int)(diy * invy), 0), Dd - 1);
        float wx = 0.f, wy = 0.f;
#pragma unroll
        for (int j = 0; j < 12; ++j) {
            int dd = d0 + j;
            wx += ((dd >= didx - 1) && (dd <= didx + 2)) ? cost[j].x : 0.f;
            wy += ((dd >= didy - 1) && (dd <= didy + 2)) ? cost[j].y : 0.f;
        }
        wx += __shfl_xor(wx, 16); wx += __shfl_xor(wx, 32);
        wy += __shfl_xor(wy, 16); wy += __shfl_xor(wy, 32);
        if (q == 0) {
            *(float2*)&out[gid] = make_float2(depx * invx, depy * invy);
            *(float2*)&out[Bb * HW + gid] = make_float2(wx * invx, wy * invy);
        }
    }
}

// ---------------- launch ----------------------------------------------------
extern "C" void kernel_launch(void* const* d_in, const int* in_sizes, int n_in,
                              void* d_out, int out_size, void* d_ws, size_t ws_size,
                              hipStream_t stream) {
    const float* features = (const float*)d_in[0];   // (V,B,C,H,W)
    const float* pm       = (const float*)d_in[1];   // (B,V,4,4)
    const float* dvals    = (const float*)d_in[2];   // (B,D)
    const float* reg_w    = (const float*)d_in[4];   // (1,C,3,3,3)
    float* outp = (float*)d_out;

    char* ws = (char*)d_ws;
    ushort* featT = (ushort*)ws;                                 // V*B*H*W*C f16
    size_t featT_bytes = (size_t)Vv * Bb * Hh * Ww * Cc * sizeof(ushort);
    float* P = (float*)(ws + featT_bytes);                       // 48 floats
    ushort* S = (ushort*)(ws + featT_bytes + 512);               // B*3*D*H*W f16
    size_t S_bytes = (size_t)Bb * 3 * Dd * HW * sizeof(ushort);
    ushort* Bfr = (ushort*)(ws + featT_bytes + 512 + S_bytes);   // 9*64*8 f16
    unsigned int* bars = (unsigned int*)(ws + featT_bytes + 512 + S_bytes + 16384);

    hipMemsetAsync(bars, 0, 512, stream);   // zero both barrier slots each launch
    hipLaunchKernelGGL(k_fused, dim3(GRID), dim3(256), 0, stream,
                       features, pm, reg_w, dvals, featT, P, Bfr, S, bars, outp);
}

// Round 7
// 362.183 us; speedup vs baseline: 2.3638x; 2.3638x over previous
//
#include <hip/hip_runtime.h>
#include <hip/hip_bf16.h>
#include <hip/hip_fp16.h>

#define Hh 128
#define Ww 160
#define Cc 32
#define Dd 48
#define Bb 2
#define Vv 3
#define HW (Hh*Ww)
#define VS 32      // vsh channel stride in f16 units: XOR swizzle keeps banks spread
#define GRID 1024  // 4 blocks/CU x 256 CU; __launch_bounds__(256,4) + 31.2KB LDS guarantee co-residency

typedef _Float16 f16x8 __attribute__((ext_vector_type(8)));
typedef float f32x4 __attribute__((ext_vector_type(4)));

// Software grid barrier for non-coherent per-XCD L2s.
// R19 fix over R18: the R18 spin polled with agent-scope ACQUIRE loads; each
// such load emits buffer_inv (L1+L2 invalidate) on gfx950 -> 1024 spinners
// continuously wiped every XCD's L2 while other blocks worked (FETCH 5.7->33MB,
// 836us). Correct discipline: RELEASE once on arrival (fetch_add), spin with
// RELAXED loads (sc1 bypass: sees remote flag, invalidates nothing), then ONE
// ACQUIRE fence per block after the flag flips, then __syncthreads.
__device__ __forceinline__ void grid_barrier(unsigned int* bar) {
    __syncthreads();
    if (threadIdx.x == 0) {
        unsigned prev = __hip_atomic_fetch_add(bar, 1u, __ATOMIC_RELEASE,
                                               __HIP_MEMORY_SCOPE_AGENT);
        if (prev == GRID - 1) {
            __hip_atomic_store(bar + 16, 1u, __ATOMIC_RELEASE,
                               __HIP_MEMORY_SCOPE_AGENT);
        } else {
            while (!__hip_atomic_load(bar + 16, __ATOMIC_RELAXED,
                                      __HIP_MEMORY_SCOPE_AGENT)) {
                __builtin_amdgcn_s_sleep(8);
            }
        }
        __builtin_amdgcn_fence(__ATOMIC_ACQUIRE, "agent");  // one L1/L2 inv per block
    }
    __syncthreads();
}

// ---------------- fused pipeline: transpose -> bar -> main -> bar -> post ---
// R18 established: fusing the 3 kernels collapses the per-iteration dispatch
// residue from ~70us to ~20us, and phase bodies are numerically correct
// (passed, absmax 4.0). Phase bodies below are verbatim R18 (= R12 k_main).
__global__ __launch_bounds__(256, 4)
void k_fused(const float* __restrict__ f, const float* __restrict__ pm,
             const float* __restrict__ wt, const float* __restrict__ dvals,
             ushort* __restrict__ featT, float* __restrict__ P,
             ushort* __restrict__ Bfr, ushort* __restrict__ S,
             unsigned int* __restrict__ bars, float* __restrict__ out) {
    __shared__ __align__(16) char smem[31232];
    const int tid = threadIdx.x;
    const int bid = blockIdx.x;

    // ================= phase 0: transpose (v,b,c,h,w) f32 -> (v,b,h,w,c) f16
    if (bid == 0 && tid < 64) {
        if (tid < Bb * (Vv - 1)) {
            int b = tid >> 1;
            int v = (tid & 1) + 1;
            const float* ref = pm + (b * Vv + 0) * 16;
            const float* src = pm + (b * Vv + v) * 16;
            float A[4][8];
            for (int i = 0; i < 4; ++i)
                for (int j = 0; j < 4; ++j) {
                    A[i][j] = ref[i * 4 + j];
                    A[i][4 + j] = (i == j) ? 1.0f : 0.0f;
                }
            for (int col = 0; col < 4; ++col) {
                int piv = col;
                for (int r = col + 1; r < 4; ++r)
                    if (fabsf(A[r][col]) > fabsf(A[piv][col])) piv = r;
                if (piv != col)
                    for (int j = 0; j < 8; ++j) { float tmp = A[col][j]; A[col][j] = A[piv][j]; A[piv][j] = tmp; }
                float inv = 1.0f / A[col][col];
                for (int j = 0; j < 8; ++j) A[col][j] *= inv;
                for (int r = 0; r < 4; ++r) {
                    if (r == col) continue;
                    float fct = A[r][col];
                    for (int j = 0; j < 8; ++j) A[r][j] -= fct * A[col][j];
                }
            }
            float Pm[3][4];
            for (int i = 0; i < 3; ++i)
                for (int j = 0; j < 4; ++j) {
                    float s = 0.f;
                    for (int k = 0; k < 4; ++k) s += src[i * 4 + k] * A[k][4 + j];
                    Pm[i][j] = s;
                }
            float* o = P + tid * 12;
            o[0] = Pm[0][0]; o[1] = Pm[0][1]; o[2] = Pm[0][2];
            o[3] = Pm[1][0]; o[4] = Pm[1][1]; o[5] = Pm[1][2];
            o[6] = Pm[2][0]; o[7] = Pm[2][1]; o[8] = Pm[2][2];
            o[9] = Pm[0][3]; o[10] = Pm[1][3]; o[11] = Pm[2][3];
        }
        int kd = tid & 15, q = tid >> 4;
        for (int tap = 0; tap < 9; ++tap) {
            ushort* dst = Bfr + (tap * 64 + tid) * 8;
            for (int j = 0; j < 8; ++j) {
                float w = (kd < 3) ? wt[(q * 8 + j) * 27 + kd * 9 + tap] : 0.f;
                __half h = __float2half(w);
                dst[j] = *(ushort*)&h;
            }
        }
    }
    if (bid < Vv * Bb * Hh) {
        float (*t)[Ww + 1] = (float(*)[Ww + 1])smem;
        int vb = bid / Hh, y = bid % Hh;
        const float* src = f + (size_t)vb * Cc * HW + (size_t)y * Ww;
        ushort* dst = featT + ((size_t)vb * Hh + y) * Ww * Cc;
        for (int i = tid; i < Cc * (Ww / 4); i += 256) {
            int c = i / (Ww / 4), x4 = (i - c * (Ww / 4)) * 4;
            float4 v = *(const float4*)(src + (size_t)c * HW + x4);
            t[c][x4] = v.x; t[c][x4 + 1] = v.y; t[c][x4 + 2] = v.z; t[c][x4 + 3] = v.w;
        }
        __syncthreads();
        for (int i = tid; i < Ww * 4; i += 256) {
            int x = i >> 2, c8 = i & 3;
            union { uint4 u; ushort s[8]; } pk;
#pragma unroll
            for (int j = 0; j < 8; ++j) {
                __half h = __float2half(t[c8 * 8 + j][x]);
                pk.s[j] = *(ushort*)&h;
            }
            *(uint4*)&dst[x * Cc + c8 * 8] = pk.u;
        }
    }
    grid_barrier(bars);

    // ================= phase 1: variance + MFMA conv (R12 body, grid-strided)
    {
        ushort* vsh = (ushort*)smem;                        // 324*32 f16 = 20736B
        unsigned int* offs = (unsigned int*)(smem + 20736); // 324*4 u32 = 5184B
        unsigned int* wgts = (unsigned int*)(smem + 25920); // 324*4 u32 = 5184B
        float* rt = (float*)(smem + 31104);                 // 24 floats
        const int lane = tid & 63;
        const int wave = tid >> 6;
        const int q = lane >> 4;
        const int n = lane & 15;
        uint4 bf[9];
#pragma unroll
        for (int tap = 0; tap < 9; ++tap)
            bf[tap] = *(const uint4*)(Bfr + ((tap * 64 + lane) << 3));

#pragma unroll 1
        for (int vb = bid; vb < 80 * Dd * Bb; vb += GRID) {
            const int tile = vb % 80;
            const int rem = vb / 80;
            const int d = rem % Dd;
            const int b = rem / Dd;
            const int tileY = tile / 10, tileX = tile - (tile / 10) * 10;

            if (tid < 24) rt[tid] = P[b * 24 + tid];
            const float depth = dvals[b * Dd + d];
            __syncthreads();

            // ---- stage A: bilinear coords for all 324 slots ----
#pragma unroll 1
            for (int p = tid; p < 324; p += 256) {
                int pyt = p / 18, pxt = p - pyt * 18;
                int gy = tileY * 16 + pyt - 1, gx = tileX * 16 + pxt - 1;
                if ((unsigned)gy >= (unsigned)Hh || (unsigned)gx >= (unsigned)Ww) continue;
#pragma unroll
                for (int vi = 0; vi < 2; ++vi) {
                    const float* M = &rt[vi * 12];
                    float fgx = (float)gx, fgy = (float)gy;
                    float rx = M[0] * fgx + M[1] * fgy + M[2];
                    float ry = M[3] * fgx + M[4] * fgy + M[5];
                    float rz = M[6] * fgx + M[7] * fgy + M[8];
                    float X = rx * depth + M[9];
                    float Y = ry * depth + M[10];
                    float Z = rz * depth + M[11];
                    float z = (fabsf(Z) < 1e-6f) ? 1e-6f : Z;
                    float u = X / z, vv = Y / z;
                    float x0f = floorf(u), y0f = floorf(vv);
                    float fx = u - x0f, fy = vv - y0f;
                    int x0 = (int)x0f, y0 = (int)y0f;
                    int x1 = x0 + 1, y1 = y0 + 1;
                    bool vx0 = (x0 >= 0) && (x0 <= Ww - 1);
                    bool vx1 = (x1 >= 0) && (x1 <= Ww - 1);
                    bool vy0 = (y0 >= 0) && (y0 <= Hh - 1);
                    bool vy1 = (y1 >= 0) && (y1 <= Hh - 1);
                    int xc0 = min(max(x0, 0), Ww - 1), xc1 = min(max(x1, 0), Ww - 1);
                    int yc0 = min(max(y0, 0), Hh - 1), yc1 = min(max(y1, 0), Hh - 1);
                    unsigned int p00 = (unsigned)(yc0 * Ww + xc0);
                    unsigned int p01 = (unsigned)(yc0 * Ww + xc1);
                    unsigned int p10 = (unsigned)(yc1 * Ww + xc0);
                    unsigned int p11 = (unsigned)(yc1 * Ww + xc1);
                    float w0 = (vx0 && vy0) ? (1.f - fx) * (1.f - fy) : 0.f;
                    float w1 = (vx1 && vy0) ? fx * (1.f - fy) : 0.f;
                    float w2 = (vx0 && vy1) ? (1.f - fx) * fy : 0.f;
                    float w3 = (vx1 && vy1) ? fx * fy : 0.f;
                    offs[p * 4 + vi * 2 + 0] = p00 | (p01 << 16);
                    offs[p * 4 + vi * 2 + 1] = p10 | (p11 << 16);
                    __half2 ha = __floats2half2_rn(w0, w1);
                    __half2 hb = __floats2half2_rn(w2, w3);
                    wgts[p * 4 + vi * 2 + 0] = *(unsigned int*)&ha;
                    wgts[p * 4 + vi * 2 + 1] = *(unsigned int*)&hb;
                }
            }
            __syncthreads();

            const ushort* b1 = featT + (size_t)(1 * Bb + b) * HW * Cc;
            const ushort* b2 = featT + (size_t)(2 * Bb + b) * HW * Cc;
            const ushort* br = featT + (size_t)b * HW * Cc;

            // ---- stage B: gather items (slot, c16 0..1): 648 items ----
#pragma unroll 1
            for (int i = tid; i < 648; i += 256) {
                int p = i >> 1, half16 = i & 1;
                int c16 = half16 << 4;
                int pyt = p / 18, pxt = p - pyt * 18;
                int gy = tileY * 16 + pyt - 1, gx = tileX * 16 + pxt - 1;
                int sw0 = ((half16 * 2 + 0) ^ (p & 3)) * 8;
                int sw1 = ((half16 * 2 + 1) ^ (p & 3)) * 8;
                ushort* dst0 = &vsh[p * VS + sw0];
                ushort* dst1 = &vsh[p * VS + sw1];
                if ((unsigned)gy >= (unsigned)Hh || (unsigned)gx >= (unsigned)Ww) {
                    *(uint4*)dst0 = make_uint4(0u, 0u, 0u, 0u);
                    *(uint4*)dst1 = make_uint4(0u, 0u, 0u, 0u);
                    continue;
                }
                uint4 oo = *(const uint4*)&offs[p * 4];
                uint4 wwp = *(const uint4*)&wgts[p * 4];
                int o00 = (int)(oo.x & 0xffffu) * Cc + c16;
                int o01 = (int)(oo.x >> 16)     * Cc + c16;
                int o10 = (int)(oo.y & 0xffffu) * Cc + c16;
                int o11 = (int)(oo.y >> 16)     * Cc + c16;
                int o20 = (int)(oo.z & 0xffffu) * Cc + c16;
                int o21 = (int)(oo.z >> 16)     * Cc + c16;
                int o30 = (int)(oo.w & 0xffffu) * Cc + c16;
                int o31 = (int)(oo.w >> 16)     * Cc + c16;
                int orf = (gy * Ww + gx) * Cc + c16;
                __half2 hv0 = *(__half2*)&wwp.x;
                __half2 hv1 = *(__half2*)&wwp.y;
                __half2 hv2 = *(__half2*)&wwp.z;
                __half2 hv3 = *(__half2*)&wwp.w;
                __half2 w00 = __half2half2(__low2half(hv0)), w01 = __half2half2(__high2half(hv0));
                __half2 w02 = __half2half2(__low2half(hv1)), w03 = __half2half2(__high2half(hv1));
                __half2 w10 = __half2half2(__low2half(hv2)), w11 = __half2half2(__high2half(hv2));
                __half2 w12 = __half2half2(__low2half(hv3)), w13 = __half2half2(__high2half(hv3));
                const __half2 third2 = __float2half2_rn(1.0f / 3.0f);
                union U { uint4 u; __half2 h[4]; };
#pragma unroll
                for (int h = 0; h < 2; ++h) {
                    int e = h * 8;
                    U R, C0, C1, C2, C3, E0, E1, E2, E3, V;
                    R.u  = *(const uint4*)(br + orf + e);
                    C0.u = *(const uint4*)(b1 + o00 + e);
                    C1.u = *(const uint4*)(b1 + o01 + e);
                    C2.u = *(const uint4*)(b1 + o10 + e);
                    C3.u = *(const uint4*)(b1 + o11 + e);
                    E0.u = *(const uint4*)(b2 + o20 + e);
                    E1.u = *(const uint4*)(b2 + o21 + e);
                    E2.u = *(const uint4*)(b2 + o30 + e);
                    E3.u = *(const uint4*)(b2 + o31 + e);
#pragma unroll
                    for (int k = 0; k < 4; ++k) {
                        __half2 s1 = __hmul2(w00, C0.h[k]);
                        s1 = __hfma2(w01, C1.h[k], s1);
                        s1 = __hfma2(w02, C2.h[k], s1);
                        s1 = __hfma2(w03, C3.h[k], s1);
                        __half2 s2 = __hmul2(w10, E0.h[k]);
                        s2 = __hfma2(w11, E1.h[k], s2);
                        s2 = __hfma2(w12, E2.h[k], s2);
                        s2 = __hfma2(w13, E3.h[k], s2);
                        __half2 r = R.h[k];
                        __half2 sum = __hadd2(__hadd2(r, s1), s2);
                        __half2 sq = __hmul2(r, r);
                        sq = __hfma2(s1, s1, sq);
                        sq = __hfma2(s2, s2, sq);
                        __half2 m = __hmul2(sum, third2);
                        __half2 var = __hfma2(__hneg2(m), m, __hmul2(sq, third2));
                        V.h[k] = var;
                    }
                    *(uint4*)(h ? dst1 : dst0) = V.u;
                }
            }
            __syncthreads();

            // ---- MFMA conv: wave covers 4 row-groups of 16 pixels ----
#pragma unroll 1
            for (int rr = 0; rr < 4; ++rr) {
                int row = wave * 4 + rr;
                f32x4 acc = {0.f, 0.f, 0.f, 0.f};
#pragma unroll
                for (int tap = 0; tap < 9; ++tap) {
                    int kh = tap / 3, kw = tap - 3 * (tap / 3);
                    int slot = (row + kh) * 18 + n + kw;
                    union { uint4 u; f16x8 v; } A, Bf;
                    A.u  = *(const uint4*)&vsh[slot * VS + (q ^ (slot & 3)) * 8];
                    Bf.u = bf[tap];
                    acc = __builtin_amdgcn_mfma_f32_16x16x32_f16(A.v, Bf.v, acc, 0, 0, 0);
                }
                if (n < 3) {
                    int gy = tileY * 16 + row;
                    int gxb = tileX * 16 + q * 4;
                    union { uint2 u; ushort s[4]; } pk;
#pragma unroll
                    for (int j = 0; j < 4; ++j) {
                        __half h = __float2half(acc[j]);
                        pk.s[j] = *(ushort*)&h;
                    }
                    *(uint2*)&S[((size_t)(b * 3 + n) * Dd + d) * HW + (size_t)gy * Ww + gxb] = pk.u;
                }
            }
            __syncthreads();
        }
    }
    grid_barrier(bars + 64);

    // ================= phase 2: cost, softmax, depth + conf =================
    if (bid < (Bb * HW) / 128) {
        const int lane = tid & 63, wave = tid >> 6;
        const int q = lane >> 4;
        const int pl = lane & 15;
        int gid = ((bid * 4 + wave) * 16 + pl) * 2;
        int b = gid / HW;
        int pix = gid - b * HW;
        const ushort* S0 = S + ((size_t)(b * 3 + 0) * Dd) * HW + pix;
        const ushort* S1 = S + ((size_t)(b * 3 + 1) * Dd) * HW + pix;
        const ushort* S2 = S + ((size_t)(b * 3 + 2) * Dd) * HW + pix;
        const int d0 = q * 12;
        float2 cost[12];
#pragma unroll
        for (int j = 0; j < 12; ++j) {
            int dd = d0 + j;
            float2 c = __half22float2(*(const __half2*)&S1[(size_t)dd * HW]);
            if (dd > 0) {
                float2 a = __half22float2(*(const __half2*)&S0[(size_t)(dd - 1) * HW]);
                c.x += a.x; c.y += a.y;
            }
            if (dd < Dd - 1) {
                float2 a = __half22float2(*(const __half2*)&S2[(size_t)(dd + 1) * HW]);
                c.x += a.x; c.y += a.y;
            }
            cost[j] = c;
        }
        float mx = cost[0].x, my = cost[0].y;
#pragma unroll
        for (int j = 1; j < 12; ++j) { mx = fmaxf(mx, cost[j].x); my = fmaxf(my, cost[j].y); }
        mx = fmaxf(mx, __shfl_xor(mx, 16)); mx = fmaxf(mx, __shfl_xor(mx, 32));
        my = fmaxf(my, __shfl_xor(my, 16)); my = fmaxf(my, __shfl_xor(my, 32));
        float sx = 0.f, sy = 0.f, depx = 0.f, depy = 0.f, dix = 0.f, diy = 0.f;
#pragma unroll
        for (int j = 0; j < 12; ++j) {
            float dv = dvals[b * Dd + d0 + j];
            float fd = (float)(d0 + j);
            float ex = __expf(cost[j].x - mx);
            float ey = __expf(cost[j].y - my);
            cost[j].x = ex; cost[j].y = ey;
            sx += ex; sy += ey;
            depx += ex * dv; depy += ey * dv;
            dix += ex * fd;  diy += ey * fd;
        }
        sx += __shfl_xor(sx, 16); sx += __shfl_xor(sx, 32);
        sy += __shfl_xor(sy, 16); sy += __shfl_xor(sy, 32);
        depx += __shfl_xor(depx, 16); depx += __shfl_xor(depx, 32);
        depy += __shfl_xor(depy, 16); depy += __shfl_xor(depy, 32);
        dix += __shfl_xor(dix, 16); dix += __shfl_xor(dix, 32);
        diy += __shfl_xor(diy, 16); diy += __shfl_xor(diy, 32);
        float invx = 1.0f / sx, invy = 1.0f / sy;
        int didx = min(max((int)(dix * invx), 0), Dd - 1);
        int didy = min(max((int)(diy * invy), 0), Dd - 1);
        float wx = 0.f, wy = 0.f;
#pragma unroll
        for (int j = 0; j < 12; ++j) {
            int dd = d0 + j;
            wx += ((dd >= didx - 1) && (dd <= didx + 2)) ? cost[j].x : 0.f;
            wy += ((dd >= didy - 1) && (dd <= didy + 2)) ? cost[j].y : 0.f;
        }
        wx += __shfl_xor(wx, 16); wx += __shfl_xor(wx, 32);
        wy += __shfl_xor(wy, 16); wy += __shfl_xor(wy, 32);
        if (q == 0) {
            *(float2*)&out[gid] = make_float2(depx * invx, depy * invy);
            *(float2*)&out[Bb * HW + gid] = make_float2(wx * invx, wy * invy);
        }
    }
}

// ---------------- launch ----------------------------------------------------
extern "C" void kernel_launch(void* const* d_in, const int* in_sizes, int n_in,
                              void* d_out, int out_size, void* d_ws, size_t ws_size,
                              hipStream_t stream) {
    const float* features = (const float*)d_in[0];   // (V,B,C,H,W)
    const float* pm       = (const float*)d_in[1];   // (B,V,4,4)
    const float* dvals    = (const float*)d_in[2];   // (B,D)
    const float* reg_w    = (const float*)d_in[4];   // (1,C,3,3,3)
    float* outp = (float*)d_out;

    char* ws = (char*)d_ws;
    ushort* featT = (ushort*)ws;                                 // V*B*H*W*C f16
    size_t featT_bytes = (size_t)Vv * Bb * Hh * Ww * Cc * sizeof(ushort);
    float* P = (float*)(ws + featT_bytes);                       // 48 floats
    ushort* S = (ushort*)(ws + featT_bytes + 512);               // B*3*D*H*W f16
    size_t S_bytes = (size_t)Bb * 3 * Dd * HW * sizeof(ushort);
    ushort* Bfr = (ushort*)(ws + featT_bytes + 512 + S_bytes);   // 9*64*8 f16
    unsigned int* bars = (unsigned int*)(ws + featT_bytes + 512 + S_bytes + 16384);

    hipMemsetAsync(bars, 0, 512, stream);   // zero both barrier slots each launch
    hipLaunchKernelGGL(k_fused, dim3(GRID), dim3(256), 0, stream,
                       features, pm, reg_w, dvals, featT, P, Bfr, S, bars, outp);
}

// Round 9
// 235.196 us; speedup vs baseline: 3.6401x; 1.5399x over previous
//
#include <hip/hip_runtime.h>
#include <hip/hip_bf16.h>
#include <hip/hip_fp16.h>

#define Hh 128
#define Ww 160
#define Cc 32
#define Dd 48
#define Bb 2
#define Vv 3
#define HW (Hh*Ww)
#define VS 32      // vsh channel stride in f16 units: XOR swizzle keeps banks spread
#define GRID 1024  // 4 blocks/CU x 256 CU; proven co-resident (R18/R19 completed)
#define NSTRIPE 32

typedef _Float16 f16x8 __attribute__((ext_vector_type(8)));
typedef float f32x4 __attribute__((ext_vector_type(4)));

// Software grid barrier for non-coherent per-XCD L2s.
// R20 fix over R19: R19's single-line relaxed spin (1024 pollers, s_sleep(8))
// saturated one L3 line (~13MB of poll FETCH) and throttled concurrent VMEM.
// Now: flag striped across 32 lines (128B apart, poll bid&31 -> 32/line),
// s_sleep(32) backoff, and the releaser publishes via ONE release fence + 32
// relaxed stores (not 32 release stores = 32 serialized wbl2).
// Semantics: arrival ACQ_REL fetch_add chains each block's dirty-L2 flush;
// releaser's release-fence + relaxed flag store, spinner's relaxed load +
// acquire fence -> fence-fence synchronization; transitively all pre-barrier
// writes visible after the post-spin fence.
// (R21 = R20 resubmitted verbatim: R20 bench died to an infra container
// failure with no counters; barrier protocol is R19-proven, so the round's
// theory/prediction stand untested rather than refuted.)
__device__ __forceinline__ void grid_barrier(unsigned int* bar) {
    __syncthreads();
    if (threadIdx.x == 0) {
        unsigned prev = __hip_atomic_fetch_add(bar, 1u, __ATOMIC_ACQ_REL,
                                               __HIP_MEMORY_SCOPE_AGENT);
        if (prev == GRID - 1) {
            __builtin_amdgcn_fence(__ATOMIC_RELEASE, "agent");
#pragma unroll
            for (int i = 0; i < NSTRIPE; ++i)
                __hip_atomic_store(bar + 64 + i * 32, 1u, __ATOMIC_RELAXED,
                                   __HIP_MEMORY_SCOPE_AGENT);
        } else {
            unsigned int* flag = bar + 64 + (blockIdx.x & (NSTRIPE - 1)) * 32;
            while (!__hip_atomic_load(flag, __ATOMIC_RELAXED,
                                      __HIP_MEMORY_SCOPE_AGENT)) {
                __builtin_amdgcn_s_sleep(32);
            }
        }
        __builtin_amdgcn_fence(__ATOMIC_ACQUIRE, "agent");  // one L1/L2 inv per block
    }
    __syncthreads();
}

// ---------------- fused pipeline: transpose -> bar -> main -> bar -> post ---
// Phase bodies verbatim R12 (numerics proven: passed R18/R19, absmax 4.0).
__global__ __launch_bounds__(256, 4)
void k_fused(const float* __restrict__ f, const float* __restrict__ pm,
             const float* __restrict__ wt, const float* __restrict__ dvals,
             ushort* __restrict__ featT, float* __restrict__ P,
             ushort* __restrict__ Bfr, ushort* __restrict__ S,
             unsigned int* __restrict__ bars, float* __restrict__ out) {
    __shared__ __align__(16) char smem[31232];
    const int tid = threadIdx.x;
    const int bid = blockIdx.x;

    // ================= phase 0: transpose (v,b,c,h,w) f32 -> (v,b,h,w,c) f16
    if (bid == 0 && tid < 64) {
        if (tid < Bb * (Vv - 1)) {
            int b = tid >> 1;
            int v = (tid & 1) + 1;
            const float* ref = pm + (b * Vv + 0) * 16;
            const float* src = pm + (b * Vv + v) * 16;
            float A[4][8];
            for (int i = 0; i < 4; ++i)
                for (int j = 0; j < 4; ++j) {
                    A[i][j] = ref[i * 4 + j];
                    A[i][4 + j] = (i == j) ? 1.0f : 0.0f;
                }
            for (int col = 0; col < 4; ++col) {
                int piv = col;
                for (int r = col + 1; r < 4; ++r)
                    if (fabsf(A[r][col]) > fabsf(A[piv][col])) piv = r;
                if (piv != col)
                    for (int j = 0; j < 8; ++j) { float tmp = A[col][j]; A[col][j] = A[piv][j]; A[piv][j] = tmp; }
                float inv = 1.0f / A[col][col];
                for (int j = 0; j < 8; ++j) A[col][j] *= inv;
                for (int r = 0; r < 4; ++r) {
                    if (r == col) continue;
                    float fct = A[r][col];
                    for (int j = 0; j < 8; ++j) A[r][j] -= fct * A[col][j];
                }
            }
            float Pm[3][4];
            for (int i = 0; i < 3; ++i)
                for (int j = 0; j < 4; ++j) {
                    float s = 0.f;
                    for (int k = 0; k < 4; ++k) s += src[i * 4 + k] * A[k][4 + j];
                    Pm[i][j] = s;
                }
            float* o = P + tid * 12;
            o[0] = Pm[0][0]; o[1] = Pm[0][1]; o[2] = Pm[0][2];
            o[3] = Pm[1][0]; o[4] = Pm[1][1]; o[5] = Pm[1][2];
            o[6] = Pm[2][0]; o[7] = Pm[2][1]; o[8] = Pm[2][2];
            o[9] = Pm[0][3]; o[10] = Pm[1][3]; o[11] = Pm[2][3];
        }
        int kd = tid & 15, q = tid >> 4;
        for (int tap = 0; tap < 9; ++tap) {
            ushort* dst = Bfr + (tap * 64 + tid) * 8;
            for (int j = 0; j < 8; ++j) {
                float w = (kd < 3) ? wt[(q * 8 + j) * 27 + kd * 9 + tap] : 0.f;
                __half h = __float2half(w);
                dst[j] = *(ushort*)&h;
            }
        }
    }
    if (bid < Vv * Bb * Hh) {
        float (*t)[Ww + 1] = (float(*)[Ww + 1])smem;
        int vb = bid / Hh, y = bid % Hh;
        const float* src = f + (size_t)vb * Cc * HW + (size_t)y * Ww;
        ushort* dst = featT + ((size_t)vb * Hh + y) * Ww * Cc;
        for (int i = tid; i < Cc * (Ww / 4); i += 256) {
            int c = i / (Ww / 4), x4 = (i - c * (Ww / 4)) * 4;
            float4 v = *(const float4*)(src + (size_t)c * HW + x4);
            t[c][x4] = v.x; t[c][x4 + 1] = v.y; t[c][x4 + 2] = v.z; t[c][x4 + 3] = v.w;
        }
        __syncthreads();
        for (int i = tid; i < Ww * 4; i += 256) {
            int x = i >> 2, c8 = i & 3;
            union { uint4 u; ushort s[8]; } pk;
#pragma unroll
            for (int j = 0; j < 8; ++j) {
                __half h = __float2half(t[c8 * 8 + j][x]);
                pk.s[j] = *(ushort*)&h;
            }
            *(uint4*)&dst[x * Cc + c8 * 8] = pk.u;
        }
    }
    grid_barrier(bars);

    // ================= phase 1: variance + MFMA conv (R12 body, grid-strided)
    {
        ushort* vsh = (ushort*)smem;                        // 324*32 f16 = 20736B
        unsigned int* offs = (unsigned int*)(smem + 20736); // 324*4 u32 = 5184B
        unsigned int* wgts = (unsigned int*)(smem + 25920); // 324*4 u32 = 5184B
        float* rt = (float*)(smem + 31104);                 // 24 floats
        const int lane = tid & 63;
        const int wave = tid >> 6;
        const int q = lane >> 4;
        const int n = lane & 15;
        uint4 bf[9];
#pragma unroll
        for (int tap = 0; tap < 9; ++tap)
            bf[tap] = *(const uint4*)(Bfr + ((tap * 64 + lane) << 3));

#pragma unroll 1
        for (int vb = bid; vb < 80 * Dd * Bb; vb += GRID) {
            const int tile = vb % 80;
            const int rem = vb / 80;
            const int d = rem % Dd;
            const int b = rem / Dd;
            const int tileY = tile / 10, tileX = tile - (tile / 10) * 10;

            if (tid < 24) rt[tid] = P[b * 24 + tid];
            const float depth = dvals[b * Dd + d];
            __syncthreads();

            // ---- stage A: bilinear coords for all 324 slots ----
#pragma unroll 1
            for (int p = tid; p < 324; p += 256) {
                int pyt = p / 18, pxt = p - pyt * 18;
                int gy = tileY * 16 + pyt - 1, gx = tileX * 16 + pxt - 1;
                if ((unsigned)gy >= (unsigned)Hh || (unsigned)gx >= (unsigned)Ww) continue;
#pragma unroll
                for (int vi = 0; vi < 2; ++vi) {
                    const float* M = &rt[vi * 12];
                    float fgx = (float)gx, fgy = (float)gy;
                    float rx = M[0] * fgx + M[1] * fgy + M[2];
                    float ry = M[3] * fgx + M[4] * fgy + M[5];
                    float rz = M[6] * fgx + M[7] * fgy + M[8];
                    float X = rx * depth + M[9];
                    float Y = ry * depth + M[10];
                    float Z = rz * depth + M[11];
                    float z = (fabsf(Z) < 1e-6f) ? 1e-6f : Z;
                    float u = X / z, vv = Y / z;
                    float x0f = floorf(u), y0f = floorf(vv);
                    float fx = u - x0f, fy = vv - y0f;
                    int x0 = (int)x0f, y0 = (int)y0f;
                    int x1 = x0 + 1, y1 = y0 + 1;
                    bool vx0 = (x0 >= 0) && (x0 <= Ww - 1);
                    bool vx1 = (x1 >= 0) && (x1 <= Ww - 1);
                    bool vy0 = (y0 >= 0) && (y0 <= Hh - 1);
                    bool vy1 = (y1 >= 0) && (y1 <= Hh - 1);
                    int xc0 = min(max(x0, 0), Ww - 1), xc1 = min(max(x1, 0), Ww - 1);
                    int yc0 = min(max(y0, 0), Hh - 1), yc1 = min(max(y1, 0), Hh - 1);
                    unsigned int p00 = (unsigned)(yc0 * Ww + xc0);
                    unsigned int p01 = (unsigned)(yc0 * Ww + xc1);
                    unsigned int p10 = (unsigned)(yc1 * Ww + xc0);
                    unsigned int p11 = (unsigned)(yc1 * Ww + xc1);
                    float w0 = (vx0 && vy0) ? (1.f - fx) * (1.f - fy) : 0.f;
                    float w1 = (vx1 && vy0) ? fx * (1.f - fy) : 0.f;
                    float w2 = (vx0 && vy1) ? (1.f - fx) * fy : 0.f;
                    float w3 = (vx1 && vy1) ? fx * fy : 0.f;
                    offs[p * 4 + vi * 2 + 0] = p00 | (p01 << 16);
                    offs[p * 4 + vi * 2 + 1] = p10 | (p11 << 16);
                    __half2 ha = __floats2half2_rn(w0, w1);
                    __half2 hb = __floats2half2_rn(w2, w3);
                    wgts[p * 4 + vi * 2 + 0] = *(unsigned int*)&ha;
                    wgts[p * 4 + vi * 2 + 1] = *(unsigned int*)&hb;
                }
            }
            __syncthreads();

            const ushort* b1 = featT + (size_t)(1 * Bb + b) * HW * Cc;
            const ushort* b2 = featT + (size_t)(2 * Bb + b) * HW * Cc;
            const ushort* br = featT + (size_t)b * HW * Cc;

            // ---- stage B: gather items (slot, c16 0..1): 648 items ----
#pragma unroll 1
            for (int i = tid; i < 648; i += 256) {
                int p = i >> 1, half16 = i & 1;
                int c16 = half16 << 4;
                int pyt = p / 18, pxt = p - pyt * 18;
                int gy = tileY * 16 + pyt - 1, gx = tileX * 16 + pxt - 1;
                int sw0 = ((half16 * 2 + 0) ^ (p & 3)) * 8;
                int sw1 = ((half16 * 2 + 1) ^ (p & 3)) * 8;
                ushort* dst0 = &vsh[p * VS + sw0];
                ushort* dst1 = &vsh[p * VS + sw1];
                if ((unsigned)gy >= (unsigned)Hh || (unsigned)gx >= (unsigned)Ww) {
                    *(uint4*)dst0 = make_uint4(0u, 0u, 0u, 0u);
                    *(uint4*)dst1 = make_uint4(0u, 0u, 0u, 0u);
                    continue;
                }
                uint4 oo = *(const uint4*)&offs[p * 4];
                uint4 wwp = *(const uint4*)&wgts[p * 4];
                int o00 = (int)(oo.x & 0xffffu) * Cc + c16;
                int o01 = (int)(oo.x >> 16)     * Cc + c16;
                int o10 = (int)(oo.y & 0xffffu) * Cc + c16;
                int o11 = (int)(oo.y >> 16)     * Cc + c16;
                int o20 = (int)(oo.z & 0xffffu) * Cc + c16;
                int o21 = (int)(oo.z >> 16)     * Cc + c16;
                int o30 = (int)(oo.w & 0xffffu) * Cc + c16;
                int o31 = (int)(oo.w >> 16)     * Cc + c16;
                int orf = (gy * Ww + gx) * Cc + c16;
                __half2 hv0 = *(__half2*)&wwp.x;
                __half2 hv1 = *(__half2*)&wwp.y;
                __half2 hv2 = *(__half2*)&wwp.z;
                __half2 hv3 = *(__half2*)&wwp.w;
                __half2 w00 = __half2half2(__low2half(hv0)), w01 = __half2half2(__high2half(hv0));
                __half2 w02 = __half2half2(__low2half(hv1)), w03 = __half2half2(__high2half(hv1));
                __half2 w10 = __half2half2(__low2half(hv2)), w11 = __half2half2(__high2half(hv2));
                __half2 w12 = __half2half2(__low2half(hv3)), w13 = __half2half2(__high2half(hv3));
                const __half2 third2 = __float2half2_rn(1.0f / 3.0f);
                union U { uint4 u; __half2 h[4]; };
#pragma unroll
                for (int h = 0; h < 2; ++h) {
                    int e = h * 8;
                    U R, C0, C1, C2, C3, E0, E1, E2, E3, V;
                    R.u  = *(const uint4*)(br + orf + e);
                    C0.u = *(const uint4*)(b1 + o00 + e);
                    C1.u = *(const uint4*)(b1 + o01 + e);
                    C2.u = *(const uint4*)(b1 + o10 + e);
                    C3.u = *(const uint4*)(b1 + o11 + e);
                    E0.u = *(const uint4*)(b2 + o20 + e);
                    E1.u = *(const uint4*)(b2 + o21 + e);
                    E2.u = *(const uint4*)(b2 + o30 + e);
                    E3.u = *(const uint4*)(b2 + o31 + e);
#pragma unroll
                    for (int k = 0; k < 4; ++k) {
                        __half2 s1 = __hmul2(w00, C0.h[k]);
                        s1 = __hfma2(w01, C1.h[k], s1);
                        s1 = __hfma2(w02, C2.h[k], s1);
                        s1 = __hfma2(w03, C3.h[k], s1);
                        __half2 s2 = __hmul2(w10, E0.h[k]);
                        s2 = __hfma2(w11, E1.h[k], s2);
                        s2 = __hfma2(w12, E2.h[k], s2);
                        s2 = __hfma2(w13, E3.h[k], s2);
                        __half2 r = R.h[k];
                        __half2 sum = __hadd2(__hadd2(r, s1), s2);
                        __half2 sq = __hmul2(r, r);
                        sq = __hfma2(s1, s1, sq);
                        sq = __hfma2(s2, s2, sq);
                        __half2 m = __hmul2(sum, third2);
                        __half2 var = __hfma2(__hneg2(m), m, __hmul2(sq, third2));
                        V.h[k] = var;
                    }
                    *(uint4*)(h ? dst1 : dst0) = V.u;
                }
            }
            __syncthreads();

            // ---- MFMA conv: wave covers 4 row-groups of 16 pixels ----
#pragma unroll 1
            for (int rr = 0; rr < 4; ++rr) {
                int row = wave * 4 + rr;
                f32x4 acc = {0.f, 0.f, 0.f, 0.f};
#pragma unroll
                for (int tap = 0; tap < 9; ++tap) {
                    int kh = tap / 3, kw = tap - 3 * (tap / 3);
                    int slot = (row + kh) * 18 + n + kw;
                    union { uint4 u; f16x8 v; } A, Bf;
                    A.u  = *(const uint4*)&vsh[slot * VS + (q ^ (slot & 3)) * 8];
                    Bf.u = bf[tap];
                    acc = __builtin_amdgcn_mfma_f32_16x16x32_f16(A.v, Bf.v, acc, 0, 0, 0);
                }
                if (n < 3) {
                    int gy = tileY * 16 + row;
                    int gxb = tileX * 16 + q * 4;
                    union { uint2 u; ushort s[4]; } pk;
#pragma unroll
                    for (int j = 0; j < 4; ++j) {
                        __half h = __float2half(acc[j]);
                        pk.s[j] = *(ushort*)&h;
                    }
                    *(uint2*)&S[((size_t)(b * 3 + n) * Dd + d) * HW + (size_t)gy * Ww + gxb] = pk.u;
                }
            }
            __syncthreads();
        }
    }
    grid_barrier(bars + 2048);

    // ================= phase 2: cost, softmax, depth + conf =================
    if (bid < (Bb * HW) / 128) {
        const int lane = tid & 63, wave = tid >> 6;
        const int q = lane >> 4;
        const int pl = lane & 15;
        int gid = ((bid * 4 + wave) * 16 + pl) * 2;
        int b = gid / HW;
        int pix = gid - b * HW;
        const ushort* S0 = S + ((size_t)(b * 3 + 0) * Dd) * HW + pix;
        const ushort* S1 = S + ((size_t)(b * 3 + 1) * Dd) * HW + pix;
        const ushort* S2 = S + ((size_t)(b * 3 + 2) * Dd) * HW + pix;
        const int d0 = q * 12;
        float2 cost[12];
#pragma unroll
        for (int j = 0; j < 12; ++j) {
            int dd = d0 + j;
            float2 c = __half22float2(*(const __half2*)&S1[(size_t)dd * HW]);
            if (dd > 0) {
                float2 a = __half22float2(*(const __half2*)&S0[(size_t)(dd - 1) * HW]);
                c.x += a.x; c.y += a.y;
            }
            if (dd < Dd - 1) {
                float2 a = __half22float2(*(const __half2*)&S2[(size_t)(dd + 1) * HW]);
                c.x += a.x; c.y += a.y;
            }
            cost[j] = c;
        }
        float mx = cost[0].x, my = cost[0].y;
#pragma unroll
        for (int j = 1; j < 12; ++j) { mx = fmaxf(mx, cost[j].x); my = fmaxf(my, cost[j].y); }
        mx = fmaxf(mx, __shfl_xor(mx, 16)); mx = fmaxf(mx, __shfl_xor(mx, 32));
        my = fmaxf(my, __shfl_xor(my, 16)); my = fmaxf(my, __shfl_xor(my, 32));
        float sx = 0.f, sy = 0.f, depx = 0.f, depy = 0.f, dix = 0.f, diy = 0.f;
#pragma unroll
        for (int j = 0; j < 12; ++j) {
            float dv = dvals[b * Dd + d0 + j];
            float fd = (float)(d0 + j);
            float ex = __expf(cost[j].x - mx);
            float ey = __expf(cost[j].y - my);
            cost[j].x = ex; cost[j].y = ey;
            sx += ex; sy += ey;
            depx += ex * dv; depy += ey * dv;
            dix += ex * fd;  diy += ey * fd;
        }
        sx += __shfl_xor(sx, 16); sx += __shfl_xor(sx, 32);
        sy += __shfl_xor(sy, 16); sy += __shfl_xor(sy, 32);
        depx += __shfl_xor(depx, 16); depx += __shfl_xor(depx, 32);
        depy += __shfl_xor(depy, 16); depy += __shfl_xor(depy, 32);
        dix += __shfl_xor(dix, 16); dix += __shfl_xor(dix, 32);
        diy += __shfl_xor(diy, 16); diy += __shfl_xor(diy, 32);
        float invx = 1.0f / sx, invy = 1.0f / sy;
        int didx = min(max((int)(dix * invx), 0), Dd - 1);
        int didy = min(max((int)(diy * invy), 0), Dd - 1);
        float wx = 0.f, wy = 0.f;
#pragma unroll
        for (int j = 0; j < 12; ++j) {
            int dd = d0 + j;
            wx += ((dd >= didx - 1) && (dd <= didx + 2)) ? cost[j].x : 0.f;
            wy += ((dd >= didy - 1) && (dd <= didy + 2)) ? cost[j].y : 0.f;
        }
        wx += __shfl_xor(wx, 16); wx += __shfl_xor(wx, 32);
        wy += __shfl_xor(wy, 16); wy += __shfl_xor(wy, 32);
        if (q == 0) {
            *(float2*)&out[gid] = make_float2(depx * invx, depy * invy);
            *(float2*)&out[Bb * HW + gid] = make_float2(wx * invx, wy * invy);
        }
    }
}

// ---------------- launch ----------------------------------------------------
extern "C" void kernel_launch(void* const* d_in, const int* in_sizes, int n_in,
                              void* d_out, int out_size, void* d_ws, size_t ws_size,
                              hipStream_t stream) {
    const float* features = (const float*)d_in[0];   // (V,B,C,H,W)
    const float* pm       = (const float*)d_in[1];   // (B,V,4,4)
    const float* dvals    = (const float*)d_in[2];   // (B,D)
    const float* reg_w    = (const float*)d_in[4];   // (1,C,3,3,3)
    float* outp = (float*)d_out;

    char* ws = (char*)d_ws;
    ushort* featT = (ushort*)ws;                                 // V*B*H*W*C f16
    size_t featT_bytes = (size_t)Vv * Bb * Hh * Ww * Cc * sizeof(ushort);
    float* P = (float*)(ws + featT_bytes);                       // 48 floats
    ushort* S = (ushort*)(ws + featT_bytes + 512);               // B*3*D*H*W f16
    size_t S_bytes = (size_t)Bb * 3 * Dd * HW * sizeof(ushort);
    ushort* Bfr = (ushort*)(ws + featT_bytes + 512 + S_bytes);   // 9*64*8 f16
    unsigned int* bars = (unsigned int*)(ws + featT_bytes + 512 + S_bytes + 16384);

    hipMemsetAsync(bars, 0, 16384, stream);   // zero both striped barrier slots
    hipLaunchKernelGGL(k_fused, dim3(GRID), dim3(256), 0, stream,
                       features, pm, reg_w, dvals, featT, P, Bfr, S, bars, outp);
}